// Round 7
// baseline (562.599 us; speedup 1.0000x reference)
//
#include <hip/hip_runtime.h>
#include <cstdint>
#include <cstddef>

#define N_USERS   100000
#define N_NODES   500000
#define DIM       64
#define N_EDGES   2000000
#define BATCH     4096
#define SCAN_B    1024
#define NBLK      ((N_NODES + SCAN_B - 1) / SCAN_B)   // 489
#define X1C_CAP   280000   // |fB| ~230k measured
#define LA_CAP    100000   // |fA| ~60k measured
#define EDG4_BLK  ((N_EDGES / 4 + 255) / 256)         // 1954 blocks, 4 edges/thread
#define CONV_BLK  ((N_NODES * 16 + 255) / 256)        // 31250 conv blocks
#define PROP_BLK  2048                                // 8192 waves = 32/CU

// ---- LDS histogram geometry (8-bit counters) ----
#define RANGES    31
#define RANGE_SZ  16384                               // nodes per range
#define RANGE_TOT (RANGES * RANGE_SZ)                 // 507904 >= N_NODES
#define HSLICES   32
#define HIST_BLK  (RANGES * HSLICES)                  // 992
#define ESLICE    (N_EDGES / HSLICES)                 // 62500
#define EINT4     (ESLICE / 4)                        // 15625
#define DEG4_BLK  ((N_NODES / 4 + 255) / 256)         // 489 (4 nodes/thread reduce)
#define CSV2_TOTAL (HIST_BLK * 33)                    // 32736: 1 scatter + 32 conv per group

typedef unsigned char uchar;
typedef unsigned short ushort;
typedef unsigned int uint;

__device__ __forceinline__ ushort f2bf(float f) {
    uint u = __float_as_uint(f);
    uint r = u + 0x7FFFu + ((u >> 16) & 1u);
    return (ushort)(r >> 16);
}
__device__ __forceinline__ float bflo(uint u) { return __uint_as_float(u << 16); }
__device__ __forceinline__ float bfhi(uint u) { return __uint_as_float(u & 0xFFFF0000u); }

// ---------- mark batch indices into three byte flags ------------------------
__global__ void k_mark(const int* __restrict__ u, const int* __restrict__ p,
                       const int* __restrict__ n, uchar* __restrict__ f3,
                       uchar* __restrict__ fA, uchar* __restrict__ fB) {
    int i = blockIdx.x * blockDim.x + threadIdx.x;
    if (i >= 3 * BATCH) return;
    int idx;
    if (i < BATCH)          idx = u[i];
    else if (i < 2 * BATCH) idx = p[i - BATCH];
    else                    idx = n[i - 2 * BATCH];
    f3[idx] = 1; fA[idx] = 1; fB[idx] = 1;
}

// ---------- phase A: LDS-range histogram (8-bit) || f3 -> fA expansion ------
// hist needs only dst, so it overlaps the LEVEL-1 expansion now.
__global__ void k_histexp(const int* __restrict__ src, const int* __restrict__ dst,
                          uchar* __restrict__ degp8, const uchar* __restrict__ f3,
                          uchar* __restrict__ fA) {
    __shared__ uint cnt[RANGE_SZ / 4];            // 4096 words = 16 KB
    if (blockIdx.x < HIST_BLK) {
        int s = blockIdx.x / RANGES;              // slice 0..31 (ranges of one slice co-resident)
        int r = blockIdx.x - s * RANGES;          // range 0..30
        for (int k = threadIdx.x; k < RANGE_SZ / 4; k += 256) cnt[k] = 0;
        __syncthreads();
        int base = r * RANGE_SZ;
        const int4* d4 = (const int4*)(dst + s * ESLICE);
        for (int t = threadIdx.x; t < EINT4; t += 256) {
            int4 d = d4[t];
            uint l;
            l = (uint)(d.x - base); if (l < RANGE_SZ) atomicAdd(&cnt[l >> 2], 1u << ((l & 3) << 3));
            l = (uint)(d.y - base); if (l < RANGE_SZ) atomicAdd(&cnt[l >> 2], 1u << ((l & 3) << 3));
            l = (uint)(d.z - base); if (l < RANGE_SZ) atomicAdd(&cnt[l >> 2], 1u << ((l & 3) << 3));
            l = (uint)(d.w - base); if (l < RANGE_SZ) atomicAdd(&cnt[l >> 2], 1u << ((l & 3) << 3));
        }
        __syncthreads();
        uint* out = (uint*)(degp8 + (size_t)s * RANGE_TOT) + r * (RANGE_SZ / 4);
        for (int k = threadIdx.x; k < RANGE_SZ / 4; k += 256) out[k] = cnt[k];
    } else {
        int t = (blockIdx.x - HIST_BLK) * blockDim.x + threadIdx.x;
        if (t < N_EDGES / 4) {
            int4 s0 = ((const int4*)src)[t];
            int4 d0 = ((const int4*)dst)[t];
            if (f3[d0.x] && !fA[s0.x]) fA[s0.x] = 1;
            if (f3[d0.y] && !fA[s0.y]) fA[s0.y] = 1;
            if (f3[d0.z] && !fA[s0.z]) fA[s0.z] = 1;
            if (f3[d0.w] && !fA[s0.w]) fA[s0.w] = 1;
        }
    }
}

// ---------- phase B: fA -> fB expansion || degp8 -> degsum reduce -----------
__global__ void k_expdeg(const int* __restrict__ src, const int* __restrict__ dst,
                         const uchar* __restrict__ fA, uchar* __restrict__ fB,
                         const uchar* __restrict__ degp8, int* __restrict__ degsum) {
    if (blockIdx.x < EDG4_BLK) {
        int t = blockIdx.x * blockDim.x + threadIdx.x;
        if (t < N_EDGES / 4) {
            int4 s0 = ((const int4*)src)[t];
            int4 d0 = ((const int4*)dst)[t];
            if (fA[d0.x] && !fB[s0.x]) fB[s0.x] = 1;
            if (fA[d0.y] && !fB[s0.y]) fB[s0.y] = 1;
            if (fA[d0.z] && !fB[s0.z]) fB[s0.z] = 1;
            if (fA[d0.w] && !fB[s0.w]) fB[s0.w] = 1;
        }
    } else {
        int j = (blockIdx.x - EDG4_BLK) * blockDim.x + threadIdx.x;  // 4 nodes/thread
        if (j < N_NODES / 4) {
            int j4 = j * 4;
            int d0 = 0, d1 = 0, d2 = 0, d3 = 0;
            #pragma unroll
            for (int s = 0; s < HSLICES; ++s) {
                uchar4 c = *(const uchar4*)(degp8 + (size_t)s * RANGE_TOT + j4);
                d0 += c.x; d1 += c.y; d2 += c.z; d3 += c.w;
            }
            ((int4*)degsum)[j] = make_int4(d0, d1, d2, d3);
        }
    }
}

// ---------- scan A: block sums of degsum (int) and fA|fB (packed) -----------
__global__ void k_scanA(const int* __restrict__ degsum, const uchar* __restrict__ fA,
                        const uchar* __restrict__ fB, int* __restrict__ bsumD,
                        int* __restrict__ bsumP) {
    __shared__ int sD[SCAN_B];
    __shared__ int sP[SCAN_B];
    int i = blockIdx.x * SCAN_B + threadIdx.x;
    int d = 0, pk = 0;
    if (i < N_NODES) { d = degsum[i]; pk = (int)fA[i] | ((int)fB[i] << 16); }
    sD[threadIdx.x] = d; sP[threadIdx.x] = pk;
    __syncthreads();
    for (int off = SCAN_B / 2; off; off >>= 1) {
        if (threadIdx.x < off) {
            sD[threadIdx.x] += sD[threadIdx.x + off];
            sP[threadIdx.x] += sP[threadIdx.x + off];
        }
        __syncthreads();
    }
    if (threadIdx.x == 0) { bsumD[blockIdx.x] = sD[0]; bsumP[blockIdx.x] = sP[0]; }
}

// ---------- scan B: exclusive scans of block sums ---------------------------
__global__ void k_scanB(const int* __restrict__ bsumD, const int* __restrict__ bsumP,
                        int* __restrict__ boffD, int* __restrict__ boffA,
                        int* __restrict__ boffB, int* __restrict__ counts) {
    __shared__ int sD[512];
    __shared__ int sA[512];
    __shared__ int sB[512];
    int d = (threadIdx.x < NBLK) ? bsumD[threadIdx.x] : 0;
    int p = (threadIdx.x < NBLK) ? bsumP[threadIdx.x] : 0;
    int a = p & 0xFFFF, b = p >> 16;
    sD[threadIdx.x] = d; sA[threadIdx.x] = a; sB[threadIdx.x] = b;
    __syncthreads();
    for (int off = 1; off < 512; off <<= 1) {
        int tD = (threadIdx.x >= off) ? sD[threadIdx.x - off] : 0;
        int tA = (threadIdx.x >= off) ? sA[threadIdx.x - off] : 0;
        int tB = (threadIdx.x >= off) ? sB[threadIdx.x - off] : 0;
        __syncthreads();
        sD[threadIdx.x] += tD; sA[threadIdx.x] += tA; sB[threadIdx.x] += tB;
        __syncthreads();
    }
    if (threadIdx.x < NBLK) {
        boffD[threadIdx.x] = sD[threadIdx.x] - d;
        boffA[threadIdx.x] = sA[threadIdx.x] - a;
        boffB[threadIdx.x] = sB[threadIdx.x] - b;
    }
    if (threadIdx.x == 511) { counts[0] = sA[511]; counts[1] = sB[511]; }
}

// ---------- scan C: rowstart/dinv + maps + worklists + per-slice cumB -------
// cumB[m*32+s] (uchar) = sum_{s'<s} degp8[s'][i] for fB node i with mapB slot m.
// Gives the atomic-free scatter its per-(slice,node) base offset.
__global__ void k_scanC(const int* __restrict__ degsum, const uchar* __restrict__ fA,
                        const uchar* __restrict__ fB, const uchar* __restrict__ degp8,
                        const int* __restrict__ boffD, const int* __restrict__ boffA,
                        const int* __restrict__ boffB,
                        int* __restrict__ rowstart, float* __restrict__ dinv,
                        int* __restrict__ mapA, int* __restrict__ mapB,
                        int4* __restrict__ listA4, int4* __restrict__ listB4,
                        uchar* __restrict__ cumB) {
    __shared__ int sD[SCAN_B];
    __shared__ int sP[SCAN_B];
    int i = blockIdx.x * SCAN_B + threadIdx.x;
    int d = 0, a = 0, b = 0;
    if (i < N_NODES) { d = degsum[i]; a = (int)fA[i]; b = (int)fB[i]; }
    sD[threadIdx.x] = d; sP[threadIdx.x] = a | (b << 16);
    __syncthreads();
    for (int off = 1; off < SCAN_B; off <<= 1) {
        int tD = (threadIdx.x >= off) ? sD[threadIdx.x - off] : 0;
        int tP = (threadIdx.x >= off) ? sP[threadIdx.x - off] : 0;
        __syncthreads();
        sD[threadIdx.x] += tD; sP[threadIdx.x] += tP;
        __syncthreads();
    }
    if (i < N_NODES) {
        int exD = sD[threadIdx.x] - d + boffD[blockIdx.x];
        int incP = sP[threadIdx.x];
        int exA = (incP & 0xFFFF) - a + boffA[blockIdx.x];
        int exB = (incP >> 16) - b + boffB[blockIdx.x];
        rowstart[i] = exD;
        float dv = (d > 0) ? rsqrtf((float)d) : 0.0f;
        dinv[i] = dv;
        mapA[i] = a ? exA : -1;
        mapB[i] = b ? exB : -1;
        int4 ent = make_int4(exD, exD + d, __float_as_int(dv), 0);
        if (a) listA4[exA] = ent;
        if (b) listB4[exB] = ent;
        if (b) {
            uchar by[HSLICES];
            uint run = 0;
            #pragma unroll
            for (int s = 0; s < HSLICES; ++s) {
                by[s] = (uchar)run;
                run += (uint)degp8[(size_t)s * RANGE_TOT + i];
            }
            uint w0[8];
            #pragma unroll
            for (int k = 0; k < 8; ++k)
                w0[k] = (uint)by[4*k] | ((uint)by[4*k+1] << 8)
                      | ((uint)by[4*k+2] << 16) | ((uint)by[4*k+3] << 24);
            uint4* cb = (uint4*)(cumB + (size_t)exB * 32);
            cb[0] = make_uint4(w0[0], w0[1], w0[2], w0[3]);
            cb[1] = make_uint4(w0[4], w0[5], w0[6], w0[7]);
        }
    }
}

// ---------- phase C: ATOMIC-FREE scatter (counting-sort ranks) || conv ------
// Groups of 33 blocks: slot 0 = scatter block g in [0,992), slots 1..32 = conv.
// Scatter block (range,slice): LDS 8-bit packed counters give the rank of each
// edge within its (slice,node); slot = rowstart[d] + cumB[mapB[d]][s] + rank.
// No global atomics anywhere -> conv's BW stream and scatter's L2 gathers
// should genuinely share the machine (R2/R3/R4/R6 showed fabric atomics don't).
__global__ void k_convscatter(const float* __restrict__ emb,
                              const float* __restrict__ dinv,
                              ushort* __restrict__ embs,
                              const int* __restrict__ src, const int* __restrict__ dst,
                              const int* __restrict__ mapB, const int* __restrict__ rowstart,
                              const uchar* __restrict__ cumB, int* __restrict__ csr_src) {
    __shared__ uint cnt[RANGE_SZ / 4];            // 16 KB rank counters
    uint bId = blockIdx.x;
    uint g = bId / 33u;
    uint r = bId - g * 33u;
    if (r == 0u) {                                // scatter block
        int s = (int)g / RANGES;
        int rg = (int)g - s * RANGES;
        for (int k = threadIdx.x; k < RANGE_SZ / 4; k += 256) cnt[k] = 0;
        __syncthreads();
        int base = rg * RANGE_SZ;
        const int4* d4 = (const int4*)(dst + s * ESLICE);
        const int4* s4 = (const int4*)(src + s * ESLICE);
        for (int t = threadIdx.x; t < EINT4; t += 256) {
            int4 d = d4[t];
            uint lx = (uint)(d.x - base), ly = (uint)(d.y - base);
            uint lz = (uint)(d.z - base), lw = (uint)(d.w - base);
            if ((lx < RANGE_SZ) || (ly < RANGE_SZ) || (lz < RANGE_SZ) || (lw < RANGE_SZ)) {
                int4 sv = s4[t];
                if (lx < RANGE_SZ) {
                    int m = mapB[d.x];
                    if (m >= 0) {
                        uint old = atomicAdd(&cnt[lx >> 2], 1u << ((lx & 3) << 3));
                        uint rank = (old >> ((lx & 3) << 3)) & 0xFFu;
                        csr_src[rowstart[d.x] + (int)cumB[(size_t)m * 32 + s] + (int)rank] = sv.x;
                    }
                }
                if (ly < RANGE_SZ) {
                    int m = mapB[d.y];
                    if (m >= 0) {
                        uint old = atomicAdd(&cnt[ly >> 2], 1u << ((ly & 3) << 3));
                        uint rank = (old >> ((ly & 3) << 3)) & 0xFFu;
                        csr_src[rowstart[d.y] + (int)cumB[(size_t)m * 32 + s] + (int)rank] = sv.y;
                    }
                }
                if (lz < RANGE_SZ) {
                    int m = mapB[d.z];
                    if (m >= 0) {
                        uint old = atomicAdd(&cnt[lz >> 2], 1u << ((lz & 3) << 3));
                        uint rank = (old >> ((lz & 3) << 3)) & 0xFFu;
                        csr_src[rowstart[d.z] + (int)cumB[(size_t)m * 32 + s] + (int)rank] = sv.z;
                    }
                }
                if (lw < RANGE_SZ) {
                    int m = mapB[d.w];
                    if (m >= 0) {
                        uint old = atomicAdd(&cnt[lw >> 2], 1u << ((lw & 3) << 3));
                        uint rank = (old >> ((lw & 3) << 3)) & 0xFFu;
                        csr_src[rowstart[d.w] + (int)cumB[(size_t)m * 32 + s] + (int)rank] = sv.w;
                    }
                }
            }
        }
    } else {                                      // conv block (pre-scaled bf16)
        int cidx = (int)(g * 32u + r - 1u);
        int c = cidx * 256 + threadIdx.x;         // 4-float chunk
        if (c < N_NODES * 16) {
            int row = c >> 4;
            float4 v = ((const float4*)emb)[c];
            float dv = dinv[row];
            uint2 o;
            o.x = (uint)f2bf(v.x * dv) | ((uint)f2bf(v.y * dv) << 16);
            o.y = (uint)f2bf(v.z * dv) | ((uint)f2bf(v.w * dv) << 16);
            ((uint2*)embs)[c] = o;
        }
    }
}

// ---------- layer 1: embs(bf16, pre-scaled) -> x1c(bf16, x1*dinv[node]) -----
__global__ void k_prop1(const ushort* __restrict__ embs, const int4* __restrict__ listB4,
                        const int* __restrict__ counts, const int* __restrict__ csr_src,
                        ushort* __restrict__ x1c) {
    int lane = threadIdx.x & 63;
    int sub = lane >> 4, q = lane & 15;
    int wv = (blockIdx.x * blockDim.x + threadIdx.x) >> 6;
    int nw = (gridDim.x * blockDim.x) >> 6;
    int cnt = counts[1];
    for (; wv < cnt; wv += nw) {
        int4 nb = listB4[wv];
        float4 acc = {0.f, 0.f, 0.f, 0.f};
        for (int i = nb.x + sub; i < nb.y; i += 4) {
            int s = csr_src[i];
            uint2 u = *(const uint2*)(embs + (size_t)s * DIM + q * 4);
            acc.x += bflo(u.x); acc.y += bfhi(u.x);
            acc.z += bflo(u.y); acc.w += bfhi(u.y);
        }
        for (int off = 16; off <= 32; off <<= 1) {
            acc.x += __shfl_xor(acc.x, off, 64);
            acc.y += __shfl_xor(acc.y, off, 64);
            acc.z += __shfl_xor(acc.z, off, 64);
            acc.w += __shfl_xor(acc.w, off, 64);
        }
        if (sub == 0) {
            float dv = __int_as_float(nb.z);
            float d2 = dv * dv;   // store x1*dinv[node] for next layer
            uint2 o;
            o.x = (uint)f2bf(acc.x * d2) | ((uint)f2bf(acc.y * d2) << 16);
            o.y = (uint)f2bf(acc.z * d2) | ((uint)f2bf(acc.w * d2) << 16);
            *(uint2*)(x1c + (size_t)wv * DIM + q * 4) = o;
        }
    }
}

// ---------- layer 2: x1c -> x2c (bf16, x2*dinv[node]) -----------------------
__global__ void k_prop2(const ushort* __restrict__ x1c, const int* __restrict__ mapB,
                        const int4* __restrict__ listA4, const int* __restrict__ counts,
                        const int* __restrict__ csr_src, ushort* __restrict__ x2c) {
    int lane = threadIdx.x & 63;
    int sub = lane >> 4, q = lane & 15;
    int wv = (blockIdx.x * blockDim.x + threadIdx.x) >> 6;
    int nw = (gridDim.x * blockDim.x) >> 6;
    int cnt = counts[0];
    for (; wv < cnt; wv += nw) {
        int4 nb = listA4[wv];
        float4 acc = {0.f, 0.f, 0.f, 0.f};
        for (int i = nb.x + sub; i < nb.y; i += 4) {
            int s = csr_src[i];
            int slot = mapB[s];
            uint2 u = *(const uint2*)(x1c + (size_t)slot * DIM + q * 4);
            acc.x += bflo(u.x); acc.y += bfhi(u.x);
            acc.z += bflo(u.y); acc.w += bfhi(u.y);
        }
        for (int off = 16; off <= 32; off <<= 1) {
            acc.x += __shfl_xor(acc.x, off, 64);
            acc.y += __shfl_xor(acc.y, off, 64);
            acc.z += __shfl_xor(acc.z, off, 64);
            acc.w += __shfl_xor(acc.w, off, 64);
        }
        if (sub == 0) {
            float dv = __int_as_float(nb.z);
            float d2 = dv * dv;
            uint2 o;
            o.x = (uint)f2bf(acc.x * d2) | ((uint)f2bf(acc.y * d2) << 16);
            o.y = (uint)f2bf(acc.z * d2) | ((uint)f2bf(acc.w * d2) << 16);
            *(uint2*)(x2c + (size_t)wv * DIM + q * 4) = o;
        }
    }
}

// ---------- fused layer 3 + loss: wave per batch item -----------------------
__device__ __forceinline__ float x3_row(const ushort* __restrict__ x2c,
                                        const int* __restrict__ mapA,
                                        const int* __restrict__ csr_src,
                                        const int4* __restrict__ listB4,
                                        const int* __restrict__ mapB,
                                        int t, int lane) {
    int4 nb = listB4[mapB[t]];
    float acc = 0.f;
    for (int i = nb.x; i < nb.y; ++i) {
        int s = csr_src[i];
        int slot = mapA[s];
        acc += __uint_as_float((uint)x2c[(size_t)slot * DIM + lane] << 16);
    }
    return acc * __int_as_float(nb.z);
}

__global__ void k_loss(const float* __restrict__ emb, const ushort* __restrict__ x1c,
                       const ushort* __restrict__ x2c,
                       const int* __restrict__ mapA, const int* __restrict__ mapB,
                       const int4* __restrict__ listB4, const int* __restrict__ csr_src,
                       const float* __restrict__ dinv,
                       const int* __restrict__ u, const int* __restrict__ p,
                       const int* __restrict__ n, float* __restrict__ out) {
    int lane = threadIdx.x & 63;
    int w = (blockIdx.x * blockDim.x + threadIdx.x) >> 6;
    if (w >= BATCH) return;
    int ui = u[w], pi = p[w], ni = n[w];
    float dvu = dinv[ui], dvp = dinv[pi], dvn = dinv[ni];
    float rdu = dvu > 0.f ? 1.f / dvu : 0.f;
    float rdp = dvp > 0.f ? 1.f / dvp : 0.f;
    float rdn = dvn > 0.f ? 1.f / dvn : 0.f;
    float ue = emb[(size_t)ui * DIM + lane];
    float pe = emb[(size_t)pi * DIM + lane];
    float ne = emb[(size_t)ni * DIM + lane];
    float u1 = __uint_as_float((uint)x1c[(size_t)mapB[ui] * DIM + lane] << 16) * rdu;
    float p1 = __uint_as_float((uint)x1c[(size_t)mapB[pi] * DIM + lane] << 16) * rdp;
    float n1 = __uint_as_float((uint)x1c[(size_t)mapB[ni] * DIM + lane] << 16) * rdn;
    float u2 = __uint_as_float((uint)x2c[(size_t)mapA[ui] * DIM + lane] << 16) * rdu;
    float p2 = __uint_as_float((uint)x2c[(size_t)mapA[pi] * DIM + lane] << 16) * rdp;
    float n2 = __uint_as_float((uint)x2c[(size_t)mapA[ni] * DIM + lane] << 16) * rdn;
    float u3 = x3_row(x2c, mapA, csr_src, listB4, mapB, ui, lane);
    float p3 = x3_row(x2c, mapA, csr_src, listB4, mapB, pi, lane);
    float n3 = x3_row(x2c, mapA, csr_src, listB4, mapB, ni, lane);
    float uall = 0.25f * (ue + u1 + u2 + u3);
    float pall = 0.25f * (pe + p1 + p2 + p3);
    float nall = 0.25f * (ne + n1 + n2 + n3);
    float pos = uall * pall;
    float neg = uall * nall;
    float sq  = ue * ue + pe * pe + ne * ne;
    for (int off = 32; off; off >>= 1) {
        pos += __shfl_xor(pos, off, 64);
        neg += __shfl_xor(neg, off, 64);
        sq  += __shfl_xor(sq,  off, 64);
    }
    if (lane == 0) {
        float z = neg - pos;
        float sp = fmaxf(z, 0.0f) + log1pf(expf(-fabsf(z)));
        float contrib = sp * (1.0f / BATCH) + 1e-4f * 0.5f * sq * (1.0f / BATCH);
        atomicAdd(out, contrib);
    }
}

extern "C" void kernel_launch(void* const* d_in, const int* in_sizes, int n_in,
                              void* d_out, int out_size, void* d_ws, size_t ws_size,
                              hipStream_t stream) {
    const float* emb  = (const float*)d_in[0];
    const int*   edge = (const int*)d_in[1];
    const int*   src  = edge;
    const int*   dst  = edge + N_EDGES;
    const int*   uidx = (const int*)d_in[2];
    const int*   pidx = (const int*)d_in[3];
    const int*   nidx = (const int*)d_in[4];
    float* out = (float*)d_out;

    // ---- workspace layout (~165 MB) ----
    char* w = (char*)d_ws;
    ushort* embs    = (ushort*)w;                w += (size_t)N_NODES * DIM * 2;   // 64 MB
    ushort* x1c     = (ushort*)w;                w += (size_t)X1C_CAP * DIM * 2;   // 35.8 MB
    ushort* x2c     = (ushort*)w;                w += (size_t)LA_CAP * DIM * 2;    // 12.8 MB
    float*  dinv    = (float*)w;                 w += (size_t)N_NODES * 4;
    int*    rowstart= (int*)w;                   w += (size_t)N_NODES * 4;
    int*    csr_src = (int*)w;                   w += (size_t)N_EDGES * 4;
    int*    mapA    = (int*)w;                   w += (size_t)N_NODES * 4;
    int*    mapB    = (int*)w;                   w += (size_t)N_NODES * 4;
    int*    degsum  = (int*)w;                   w += (size_t)N_NODES * 4;
    int4*   listA4  = (int4*)w;                  w += (size_t)LA_CAP * 16;
    int4*   listB4  = (int4*)w;                  w += (size_t)X1C_CAP * 16;
    uchar*  degp8   = (uchar*)w;                 w += (size_t)HSLICES * RANGE_TOT; // 15.5 MB, NOT zeroed (fully overwritten)
    uchar*  cumB    = (uchar*)w;                 w += (size_t)X1C_CAP * 32;        // 8.96 MB, NOT zeroed (only fB rows read)
    // --- zeroed region (single memset): flags only ---
    char*   zbase   = w;
    uchar*  flags   = (uchar*)w;                 w += (size_t)3 * N_NODES;         // 1.5 MB
    uchar*  f3 = flags;
    uchar*  fA = flags + N_NODES;
    uchar*  fB = flags + 2 * N_NODES;
    size_t  zbytes  = (size_t)(w - zbase);
    int*    bsumD   = (int*)w;                   w += (size_t)NBLK * 4;
    int*    boffD   = (int*)w;                   w += (size_t)NBLK * 4;
    int*    bsumP   = (int*)w;                   w += (size_t)NBLK * 4;
    int*    boffA   = (int*)w;                   w += (size_t)NBLK * 4;
    int*    boffB   = (int*)w;                   w += (size_t)NBLK * 4;
    int*    counts  = (int*)w;                   w += 16;   // [0]=|fA|, [1]=|fB|

    hipMemsetAsync(zbase, 0, zbytes, stream);
    hipMemsetAsync(out, 0, 4, stream);

    // batch marks
    k_mark<<<(3 * BATCH + 255) / 256, 256, 0, stream>>>(uidx, pidx, nidx, f3, fA, fB);

    // phase A: histogram (dst only) || level-1 expansion (f3 -> fA)
    k_histexp<<<HIST_BLK + EDG4_BLK, 256, 0, stream>>>(src, dst, degp8, f3, fA);

    // phase B: level-2 expansion (fA -> fB) || degp8 -> degsum reduce
    k_expdeg<<<EDG4_BLK + DEG4_BLK, 256, 0, stream>>>(src, dst, fA, fB, degp8, degsum);

    // scan trio: CSR offsets + dinv + maps + worklists + per-slice cumB
    k_scanA<<<NBLK, SCAN_B, 0, stream>>>(degsum, fA, fB, bsumD, bsumP);
    k_scanB<<<1, 512, 0, stream>>>(bsumD, bsumP, boffD, boffA, boffB, counts);
    k_scanC<<<NBLK, SCAN_B, 0, stream>>>(degsum, fA, fB, degp8, boffD, boffA, boffB,
                                         rowstart, dinv, mapA, mapB, listA4, listB4,
                                         cumB);

    // phase C: atomic-free counting-sort CSR fill || pre-scaled bf16 staging
    k_convscatter<<<CSV2_TOTAL, 256, 0, stream>>>(
        emb, dinv, embs, src, dst, mapB, rowstart, cumB, csr_src);

    // sparse propagation (persistent grid-stride)
    k_prop1<<<PROP_BLK, 256, 0, stream>>>(embs, listB4, counts, csr_src, x1c);
    k_prop2<<<PROP_BLK, 256, 0, stream>>>(x1c, mapB, listA4, counts, csr_src, x2c);

    // fused layer-3 + loss
    k_loss<<<(BATCH * 64 + 255) / 256, 256, 0, stream>>>(
        emb, x1c, x2c, mapA, mapB, listB4, csr_src, dinv, uidx, pidx, nidx, out);
}

// Round 8
// 449.104 us; speedup vs baseline: 1.2527x; 1.2527x over previous
//
#include <hip/hip_runtime.h>
#include <cstdint>
#include <cstddef>

#define N_USERS   100000
#define N_NODES   500000
#define DIM       64
#define N_EDGES   2000000
#define BATCH     4096
#define SCAN_B    1024
#define NBLK      ((N_NODES + SCAN_B - 1) / SCAN_B)   // 489
#define X1C_CAP   280000   // |fB| ~230k measured
#define LA_CAP    100000   // |fA| ~60k measured
#define EDG4_BLK  ((N_EDGES / 4 + 255) / 256)         // 1954 blocks, 4 edges/thread
#define PROP_BLK  2048                                // 8192 waves = 32/CU

// ---- LDS histogram geometry (8-bit counters) ----
#define RANGES    31
#define RANGE_SZ  16384                               // nodes per range
#define RANGE_TOT (RANGES * RANGE_SZ)                 // 507904 >= N_NODES
#define HSLICES   32
#define HIST_BLK  (RANGES * HSLICES)                  // 992
#define ESLICE    (N_EDGES / HSLICES)                 // 62500
#define EINT4     (ESLICE / 4)                        // 15625
#define DEG4_BLK  ((N_NODES / 4 + 255) / 256)         // 489 (4 nodes/thread reduce)

// ---- phase-4 interleave geometry: {exp2, degreduce} 1 : 13 conv ----
#define NSPECIAL  (EDG4_BLK + DEG4_BLK)               // 2443
#define ECD_TOTAL (NSPECIAL * 14)                     // 34202 (conv cap 31759 >= 31250)

typedef unsigned char uchar;
typedef unsigned short ushort;
typedef unsigned int uint;

__device__ __forceinline__ ushort f2bf(float f) {
    uint u = __float_as_uint(f);
    uint r = u + 0x7FFFu + ((u >> 16) & 1u);
    return (ushort)(r >> 16);
}
__device__ __forceinline__ float bflo(uint u) { return __uint_as_float(u << 16); }
__device__ __forceinline__ float bfhi(uint u) { return __uint_as_float(u & 0xFFFF0000u); }

// ---------- mark batch indices into three byte flags ------------------------
__global__ void k_mark(const int* __restrict__ u, const int* __restrict__ p,
                       const int* __restrict__ n, uchar* __restrict__ f3,
                       uchar* __restrict__ fA, uchar* __restrict__ fB) {
    int i = blockIdx.x * blockDim.x + threadIdx.x;
    if (i >= 3 * BATCH) return;
    int idx;
    if (i < BATCH)          idx = u[i];
    else if (i < 2 * BATCH) idx = p[i - BATCH];
    else                    idx = n[i - 2 * BATCH];
    f3[idx] = 1; fA[idx] = 1; fB[idx] = 1;
}

// ---------- phase A: LDS-range histogram (8-bit) || f3 -> fA expansion ------
// hist's 31x dst re-reads depend on cache locality -> its partner must be
// small/linear (exp1, 16 MB). R7 proved a 192-MB stream partner thrashes it.
__global__ void k_histexp(const int* __restrict__ src, const int* __restrict__ dst,
                          uchar* __restrict__ degp8, const uchar* __restrict__ f3,
                          uchar* __restrict__ fA) {
    __shared__ uint cnt[RANGE_SZ / 4];            // 4096 words = 16 KB
    if (blockIdx.x < HIST_BLK) {
        int s = blockIdx.x / RANGES;              // slice 0..31
        int r = blockIdx.x - s * RANGES;          // range 0..30
        for (int k = threadIdx.x; k < RANGE_SZ / 4; k += 256) cnt[k] = 0;
        __syncthreads();
        int base = r * RANGE_SZ;
        const int4* d4 = (const int4*)(dst + s * ESLICE);
        for (int t = threadIdx.x; t < EINT4; t += 256) {
            int4 d = d4[t];
            uint l;
            l = (uint)(d.x - base); if (l < RANGE_SZ) atomicAdd(&cnt[l >> 2], 1u << ((l & 3) << 3));
            l = (uint)(d.y - base); if (l < RANGE_SZ) atomicAdd(&cnt[l >> 2], 1u << ((l & 3) << 3));
            l = (uint)(d.z - base); if (l < RANGE_SZ) atomicAdd(&cnt[l >> 2], 1u << ((l & 3) << 3));
            l = (uint)(d.w - base); if (l < RANGE_SZ) atomicAdd(&cnt[l >> 2], 1u << ((l & 3) << 3));
        }
        __syncthreads();
        uint* out = (uint*)(degp8 + (size_t)s * RANGE_TOT) + r * (RANGE_SZ / 4);
        for (int k = threadIdx.x; k < RANGE_SZ / 4; k += 256) out[k] = cnt[k];
    } else {
        int t = (blockIdx.x - HIST_BLK) * blockDim.x + threadIdx.x;
        if (t < N_EDGES / 4) {
            int4 s0 = ((const int4*)src)[t];
            int4 d0 = ((const int4*)dst)[t];
            if (f3[d0.x] && !fA[s0.x]) fA[s0.x] = 1;
            if (f3[d0.y] && !fA[s0.y]) fA[s0.y] = 1;
            if (f3[d0.z] && !fA[s0.z]) fA[s0.z] = 1;
            if (f3[d0.w] && !fA[s0.w]) fA[s0.w] = 1;
        }
    }
}

// ---------- phase B: exp2 (fA->fB) || conv-UNSCALED || degp8->degsum --------
// All three are atomic-free plain-memory phases with no re-read locality ->
// genuine sharing expected (the scatter is deliberately NOT here: fabric
// atomics throttle co-residents, R2/R3/R6). conv is unscaled (no dinv dep);
// prop1 re-applies dinv[src] via fmaf (R3-proven).
__global__ void k_expconvdeg(const int* __restrict__ src, const int* __restrict__ dst,
                             const uchar* __restrict__ fA, uchar* __restrict__ fB,
                             const uchar* __restrict__ degp8, int* __restrict__ degsum,
                             const float* __restrict__ emb, ushort* __restrict__ embs) {
    uint b = blockIdx.x;
    uint g = b / 14u;
    uint r = b - g * 14u;
    if (r == 0u) {
        if (g < EDG4_BLK) {                       // exp2 block
            int t = (int)g * 256 + threadIdx.x;
            if (t < N_EDGES / 4) {
                int4 s0 = ((const int4*)src)[t];
                int4 d0 = ((const int4*)dst)[t];
                if (fA[d0.x] && !fB[s0.x]) fB[s0.x] = 1;
                if (fA[d0.y] && !fB[s0.y]) fB[s0.y] = 1;
                if (fA[d0.z] && !fB[s0.z]) fB[s0.z] = 1;
                if (fA[d0.w] && !fB[s0.w]) fB[s0.w] = 1;
            }
        } else {                                  // degreduce block
            int j = (int)(g - EDG4_BLK) * 256 + threadIdx.x;   // 4 nodes/thread
            if (j < N_NODES / 4) {
                int j4 = j * 4;
                int d0 = 0, d1 = 0, d2 = 0, d3 = 0;
                #pragma unroll
                for (int s = 0; s < HSLICES; ++s) {
                    uchar4 c = *(const uchar4*)(degp8 + (size_t)s * RANGE_TOT + j4);
                    d0 += c.x; d1 += c.y; d2 += c.z; d3 += c.w;
                }
                ((int4*)degsum)[j] = make_int4(d0, d1, d2, d3);
            }
        }
    } else {                                      // conv block (UNSCALED bf16)
        int c = (int)(g * 13u + r - 1u) * 256 + threadIdx.x;   // 4-float chunk
        if (c < N_NODES * 16) {
            float4 v = ((const float4*)emb)[c];
            uint2 o;
            o.x = (uint)f2bf(v.x) | ((uint)f2bf(v.y) << 16);
            o.y = (uint)f2bf(v.z) | ((uint)f2bf(v.w) << 16);
            ((uint2*)embs)[c] = o;
        }
    }
}

// ---------- scan A: block sums of degsum (int) and fA|fB (packed) -----------
__global__ void k_scanA(const int* __restrict__ degsum, const uchar* __restrict__ fA,
                        const uchar* __restrict__ fB, int* __restrict__ bsumD,
                        int* __restrict__ bsumP) {
    __shared__ int sD[SCAN_B];
    __shared__ int sP[SCAN_B];
    int i = blockIdx.x * SCAN_B + threadIdx.x;
    int d = 0, pk = 0;
    if (i < N_NODES) { d = degsum[i]; pk = (int)fA[i] | ((int)fB[i] << 16); }
    sD[threadIdx.x] = d; sP[threadIdx.x] = pk;
    __syncthreads();
    for (int off = SCAN_B / 2; off; off >>= 1) {
        if (threadIdx.x < off) {
            sD[threadIdx.x] += sD[threadIdx.x + off];
            sP[threadIdx.x] += sP[threadIdx.x + off];
        }
        __syncthreads();
    }
    if (threadIdx.x == 0) { bsumD[blockIdx.x] = sD[0]; bsumP[blockIdx.x] = sP[0]; }
}

// ---------- scan B: exclusive scans of block sums ---------------------------
__global__ void k_scanB(const int* __restrict__ bsumD, const int* __restrict__ bsumP,
                        int* __restrict__ boffD, int* __restrict__ boffA,
                        int* __restrict__ boffB, int* __restrict__ counts) {
    __shared__ int sD[512];
    __shared__ int sA[512];
    __shared__ int sB[512];
    int d = (threadIdx.x < NBLK) ? bsumD[threadIdx.x] : 0;
    int p = (threadIdx.x < NBLK) ? bsumP[threadIdx.x] : 0;
    int a = p & 0xFFFF, b = p >> 16;
    sD[threadIdx.x] = d; sA[threadIdx.x] = a; sB[threadIdx.x] = b;
    __syncthreads();
    for (int off = 1; off < 512; off <<= 1) {
        int tD = (threadIdx.x >= off) ? sD[threadIdx.x - off] : 0;
        int tA = (threadIdx.x >= off) ? sA[threadIdx.x - off] : 0;
        int tB = (threadIdx.x >= off) ? sB[threadIdx.x - off] : 0;
        __syncthreads();
        sD[threadIdx.x] += tD; sA[threadIdx.x] += tA; sB[threadIdx.x] += tB;
        __syncthreads();
    }
    if (threadIdx.x < NBLK) {
        boffD[threadIdx.x] = sD[threadIdx.x] - d;
        boffA[threadIdx.x] = sA[threadIdx.x] - a;
        boffB[threadIdx.x] = sB[threadIdx.x] - b;
    }
    if (threadIdx.x == 511) { counts[0] = sA[511]; counts[1] = sB[511]; }
}

// ---------- scan C: rowstart/dinv + mapA/mapB + packed worklists ------------
__global__ void k_scanC(const int* __restrict__ degsum, const uchar* __restrict__ fA,
                        const uchar* __restrict__ fB,
                        const int* __restrict__ boffD, const int* __restrict__ boffA,
                        const int* __restrict__ boffB,
                        int* __restrict__ rowstart, float* __restrict__ dinv,
                        int* __restrict__ mapA, int* __restrict__ mapB,
                        int4* __restrict__ listA4, int4* __restrict__ listB4) {
    __shared__ int sD[SCAN_B];
    __shared__ int sP[SCAN_B];
    int i = blockIdx.x * SCAN_B + threadIdx.x;
    int d = 0, a = 0, b = 0;
    if (i < N_NODES) { d = degsum[i]; a = (int)fA[i]; b = (int)fB[i]; }
    sD[threadIdx.x] = d; sP[threadIdx.x] = a | (b << 16);
    __syncthreads();
    for (int off = 1; off < SCAN_B; off <<= 1) {
        int tD = (threadIdx.x >= off) ? sD[threadIdx.x - off] : 0;
        int tP = (threadIdx.x >= off) ? sP[threadIdx.x - off] : 0;
        __syncthreads();
        sD[threadIdx.x] += tD; sP[threadIdx.x] += tP;
        __syncthreads();
    }
    if (i < N_NODES) {
        int exD = sD[threadIdx.x] - d + boffD[blockIdx.x];
        int incP = sP[threadIdx.x];
        int exA = (incP & 0xFFFF) - a + boffA[blockIdx.x];
        int exB = (incP >> 16) - b + boffB[blockIdx.x];
        rowstart[i] = exD;
        float dv = (d > 0) ? rsqrtf((float)d) : 0.0f;
        dinv[i] = dv;
        mapA[i] = a ? exA : -1;
        mapB[i] = b ? exB : -1;
        int4 ent = make_int4(exD, exD + d, __float_as_int(dv), 0);
        if (a) listA4[exA] = ent;
        if (b) listB4[exB] = ent;
    }
}

// ---------- masked scatter ALONE (atomic-rate-bound; partners pay sum) ------
__global__ void k_scatter(const int* __restrict__ src, const int* __restrict__ dst,
                          const uchar* __restrict__ fB, int* __restrict__ rowstart,
                          int* __restrict__ csr_src) {
    int t = blockIdx.x * blockDim.x + threadIdx.x;
    if (t < N_EDGES / 4) {
        int4 s0 = ((const int4*)src)[t];
        int4 d0 = ((const int4*)dst)[t];
        if (fB[d0.x]) csr_src[atomicAdd(&rowstart[d0.x], 1)] = s0.x;
        if (fB[d0.y]) csr_src[atomicAdd(&rowstart[d0.y], 1)] = s0.y;
        if (fB[d0.z]) csr_src[atomicAdd(&rowstart[d0.z], 1)] = s0.z;
        if (fB[d0.w]) csr_src[atomicAdd(&rowstart[d0.w], 1)] = s0.w;
    }
}

// ---------- layer 1: embs(bf16, UNSCALED) -> x1c(bf16, x1*dinv[node]) -------
// dinv[src] applied here via fmaf (R3-proven off-top-5)
__global__ void k_prop1(const ushort* __restrict__ embs, const int4* __restrict__ listB4,
                        const int* __restrict__ counts, const int* __restrict__ csr_src,
                        const float* __restrict__ dinv, ushort* __restrict__ x1c) {
    int lane = threadIdx.x & 63;
    int sub = lane >> 4, q = lane & 15;
    int wv = (blockIdx.x * blockDim.x + threadIdx.x) >> 6;
    int nw = (gridDim.x * blockDim.x) >> 6;
    int cnt = counts[1];
    for (; wv < cnt; wv += nw) {
        int4 nb = listB4[wv];
        float4 acc = {0.f, 0.f, 0.f, 0.f};
        for (int i = nb.x + sub; i < nb.y; i += 4) {
            int s = csr_src[i];
            float dvs = dinv[s];
            uint2 u = *(const uint2*)(embs + (size_t)s * DIM + q * 4);
            acc.x = fmaf(bflo(u.x), dvs, acc.x);
            acc.y = fmaf(bfhi(u.x), dvs, acc.y);
            acc.z = fmaf(bflo(u.y), dvs, acc.z);
            acc.w = fmaf(bfhi(u.y), dvs, acc.w);
        }
        for (int off = 16; off <= 32; off <<= 1) {
            acc.x += __shfl_xor(acc.x, off, 64);
            acc.y += __shfl_xor(acc.y, off, 64);
            acc.z += __shfl_xor(acc.z, off, 64);
            acc.w += __shfl_xor(acc.w, off, 64);
        }
        if (sub == 0) {
            float dv = __int_as_float(nb.z);
            float d2 = dv * dv;   // store x1*dinv[node] for next layer
            uint2 o;
            o.x = (uint)f2bf(acc.x * d2) | ((uint)f2bf(acc.y * d2) << 16);
            o.y = (uint)f2bf(acc.z * d2) | ((uint)f2bf(acc.w * d2) << 16);
            *(uint2*)(x1c + (size_t)wv * DIM + q * 4) = o;
        }
    }
}

// ---------- layer 2: x1c -> x2c (bf16, x2*dinv[node]) -----------------------
__global__ void k_prop2(const ushort* __restrict__ x1c, const int* __restrict__ mapB,
                        const int4* __restrict__ listA4, const int* __restrict__ counts,
                        const int* __restrict__ csr_src, ushort* __restrict__ x2c) {
    int lane = threadIdx.x & 63;
    int sub = lane >> 4, q = lane & 15;
    int wv = (blockIdx.x * blockDim.x + threadIdx.x) >> 6;
    int nw = (gridDim.x * blockDim.x) >> 6;
    int cnt = counts[0];
    for (; wv < cnt; wv += nw) {
        int4 nb = listA4[wv];
        float4 acc = {0.f, 0.f, 0.f, 0.f};
        for (int i = nb.x + sub; i < nb.y; i += 4) {
            int s = csr_src[i];
            int slot = mapB[s];
            uint2 u = *(const uint2*)(x1c + (size_t)slot * DIM + q * 4);
            acc.x += bflo(u.x); acc.y += bfhi(u.x);
            acc.z += bflo(u.y); acc.w += bfhi(u.y);
        }
        for (int off = 16; off <= 32; off <<= 1) {
            acc.x += __shfl_xor(acc.x, off, 64);
            acc.y += __shfl_xor(acc.y, off, 64);
            acc.z += __shfl_xor(acc.z, off, 64);
            acc.w += __shfl_xor(acc.w, off, 64);
        }
        if (sub == 0) {
            float dv = __int_as_float(nb.z);
            float d2 = dv * dv;
            uint2 o;
            o.x = (uint)f2bf(acc.x * d2) | ((uint)f2bf(acc.y * d2) << 16);
            o.y = (uint)f2bf(acc.z * d2) | ((uint)f2bf(acc.w * d2) << 16);
            *(uint2*)(x2c + (size_t)wv * DIM + q * 4) = o;
        }
    }
}

// ---------- fused layer 3 + loss: wave per batch item -----------------------
__device__ __forceinline__ float x3_row(const ushort* __restrict__ x2c,
                                        const int* __restrict__ mapA,
                                        const int* __restrict__ csr_src,
                                        const int4* __restrict__ listB4,
                                        const int* __restrict__ mapB,
                                        int t, int lane) {
    int4 nb = listB4[mapB[t]];
    float acc = 0.f;
    for (int i = nb.x; i < nb.y; ++i) {
        int s = csr_src[i];
        int slot = mapA[s];
        acc += __uint_as_float((uint)x2c[(size_t)slot * DIM + lane] << 16);
    }
    return acc * __int_as_float(nb.z);
}

__global__ void k_loss(const float* __restrict__ emb, const ushort* __restrict__ x1c,
                       const ushort* __restrict__ x2c,
                       const int* __restrict__ mapA, const int* __restrict__ mapB,
                       const int4* __restrict__ listB4, const int* __restrict__ csr_src,
                       const float* __restrict__ dinv,
                       const int* __restrict__ u, const int* __restrict__ p,
                       const int* __restrict__ n, float* __restrict__ out) {
    int lane = threadIdx.x & 63;
    int w = (blockIdx.x * blockDim.x + threadIdx.x) >> 6;
    if (w >= BATCH) return;
    int ui = u[w], pi = p[w], ni = n[w];
    float dvu = dinv[ui], dvp = dinv[pi], dvn = dinv[ni];
    float rdu = dvu > 0.f ? 1.f / dvu : 0.f;
    float rdp = dvp > 0.f ? 1.f / dvp : 0.f;
    float rdn = dvn > 0.f ? 1.f / dvn : 0.f;
    float ue = emb[(size_t)ui * DIM + lane];
    float pe = emb[(size_t)pi * DIM + lane];
    float ne = emb[(size_t)ni * DIM + lane];
    float u1 = __uint_as_float((uint)x1c[(size_t)mapB[ui] * DIM + lane] << 16) * rdu;
    float p1 = __uint_as_float((uint)x1c[(size_t)mapB[pi] * DIM + lane] << 16) * rdp;
    float n1 = __uint_as_float((uint)x1c[(size_t)mapB[ni] * DIM + lane] << 16) * rdn;
    float u2 = __uint_as_float((uint)x2c[(size_t)mapA[ui] * DIM + lane] << 16) * rdu;
    float p2 = __uint_as_float((uint)x2c[(size_t)mapA[pi] * DIM + lane] << 16) * rdp;
    float n2 = __uint_as_float((uint)x2c[(size_t)mapA[ni] * DIM + lane] << 16) * rdn;
    float u3 = x3_row(x2c, mapA, csr_src, listB4, mapB, ui, lane);
    float p3 = x3_row(x2c, mapA, csr_src, listB4, mapB, pi, lane);
    float n3 = x3_row(x2c, mapA, csr_src, listB4, mapB, ni, lane);
    float uall = 0.25f * (ue + u1 + u2 + u3);
    float pall = 0.25f * (pe + p1 + p2 + p3);
    float nall = 0.25f * (ne + n1 + n2 + n3);
    float pos = uall * pall;
    float neg = uall * nall;
    float sq  = ue * ue + pe * pe + ne * ne;
    for (int off = 32; off; off >>= 1) {
        pos += __shfl_xor(pos, off, 64);
        neg += __shfl_xor(neg, off, 64);
        sq  += __shfl_xor(sq,  off, 64);
    }
    if (lane == 0) {
        float z = neg - pos;
        float sp = fmaxf(z, 0.0f) + log1pf(expf(-fabsf(z)));
        float contrib = sp * (1.0f / BATCH) + 1e-4f * 0.5f * sq * (1.0f / BATCH);
        atomicAdd(out, contrib);
    }
}

extern "C" void kernel_launch(void* const* d_in, const int* in_sizes, int n_in,
                              void* d_out, int out_size, void* d_ws, size_t ws_size,
                              hipStream_t stream) {
    const float* emb  = (const float*)d_in[0];
    const int*   edge = (const int*)d_in[1];
    const int*   src  = edge;
    const int*   dst  = edge + N_EDGES;
    const int*   uidx = (const int*)d_in[2];
    const int*   pidx = (const int*)d_in[3];
    const int*   nidx = (const int*)d_in[4];
    float* out = (float*)d_out;

    // ---- workspace layout (~160 MB) ----
    char* w = (char*)d_ws;
    ushort* embs    = (ushort*)w;                w += (size_t)N_NODES * DIM * 2;   // 64 MB
    ushort* x1c     = (ushort*)w;                w += (size_t)X1C_CAP * DIM * 2;   // 35.8 MB
    ushort* x2c     = (ushort*)w;                w += (size_t)LA_CAP * DIM * 2;    // 12.8 MB
    float*  dinv    = (float*)w;                 w += (size_t)N_NODES * 4;
    int*    rowstart= (int*)w;                   w += (size_t)N_NODES * 4;
    int*    csr_src = (int*)w;                   w += (size_t)N_EDGES * 4;
    int*    mapA    = (int*)w;                   w += (size_t)N_NODES * 4;
    int*    mapB    = (int*)w;                   w += (size_t)N_NODES * 4;
    int*    degsum  = (int*)w;                   w += (size_t)N_NODES * 4;
    int4*   listA4  = (int4*)w;                  w += (size_t)LA_CAP * 16;
    int4*   listB4  = (int4*)w;                  w += (size_t)X1C_CAP * 16;
    uchar*  degp8   = (uchar*)w;                 w += (size_t)HSLICES * RANGE_TOT; // 15.5 MB, NOT zeroed (fully overwritten)
    // --- zeroed region (single memset): flags only ---
    char*   zbase   = w;
    uchar*  flags   = (uchar*)w;                 w += (size_t)3 * N_NODES;         // 1.5 MB
    uchar*  f3 = flags;
    uchar*  fA = flags + N_NODES;
    uchar*  fB = flags + 2 * N_NODES;
    size_t  zbytes  = (size_t)(w - zbase);
    int*    bsumD   = (int*)w;                   w += (size_t)NBLK * 4;
    int*    boffD   = (int*)w;                   w += (size_t)NBLK * 4;
    int*    bsumP   = (int*)w;                   w += (size_t)NBLK * 4;
    int*    boffA   = (int*)w;                   w += (size_t)NBLK * 4;
    int*    boffB   = (int*)w;                   w += (size_t)NBLK * 4;
    int*    counts  = (int*)w;                   w += 16;   // [0]=|fA|, [1]=|fB|

    hipMemsetAsync(zbase, 0, zbytes, stream);
    hipMemsetAsync(out, 0, 4, stream);

    // batch marks
    k_mark<<<(3 * BATCH + 255) / 256, 256, 0, stream>>>(uidx, pidx, nidx, f3, fA, fB);

    // phase A: histogram (dst only, cache-dependent) || exp1 (linear, small)
    k_histexp<<<HIST_BLK + EDG4_BLK, 256, 0, stream>>>(src, dst, degp8, f3, fA);

    // phase B: exp2 || conv-unscaled || degp8->degsum (all atomic-free)
    k_expconvdeg<<<ECD_TOTAL, 256, 0, stream>>>(src, dst, fA, fB, degp8, degsum,
                                                emb, embs);

    // scan trio: CSR offsets + dinv + maps + worklists
    k_scanA<<<NBLK, SCAN_B, 0, stream>>>(degsum, fA, fB, bsumD, bsumP);
    k_scanB<<<1, 512, 0, stream>>>(bsumD, bsumP, boffD, boffA, boffB, counts);
    k_scanC<<<NBLK, SCAN_B, 0, stream>>>(degsum, fA, fB, boffD, boffA, boffB,
                                         rowstart, dinv, mapA, mapB, listA4, listB4);

    // masked atomic CSR fill, ALONE (fabric atomics throttle any co-resident)
    k_scatter<<<EDG4_BLK, 256, 0, stream>>>(src, dst, fB, rowstart, csr_src);

    // sparse propagation (persistent grid-stride)
    k_prop1<<<PROP_BLK, 256, 0, stream>>>(embs, listB4, counts, csr_src, dinv, x1c);
    k_prop2<<<PROP_BLK, 256, 0, stream>>>(x1c, mapB, listA4, counts, csr_src, x2c);

    // fused layer-3 + loss
    k_loss<<<(BATCH * 64 + 255) / 256, 256, 0, stream>>>(
        emb, x1c, x2c, mapA, mapB, listB4, csr_src, dinv, uidx, pidx, nidx, out);
}